// Round 1
// baseline (883.504 us; speedup 1.0000x reference)
//
#include <hip/hip_runtime.h>
#include <hip/hip_bf16.h>

#define BB 512
#define TT 512
#define HH 100
#define DI 101
#define DOUT 2
#define BT (BB * TT)

// ---------------------------------------------------------------------------
// Kernel 1: xp[bt, i] = dot(input[bt, :], W_x[i, :]) + b[i]
// lane = output state i (100 active of 128). W_x row held in VGPRs (101 regs).
// input row address is wave-uniform -> scalar loads through K$.
// Stores coalesced (lane-contiguous). xp written into the hstore region of
// d_out (overwritten in-place later by the scan kernel).
// ---------------------------------------------------------------------------
__global__ __launch_bounds__(128) void k_inproj(
    const float* __restrict__ in, const float* __restrict__ Wx,
    const float* __restrict__ bias, float* __restrict__ xp,
    int rows_per_block) {
  const int i = threadIdx.x;
  const bool active = (i < HH);

  float wx[DI];
  float bi = 0.f;
  if (active) {
#pragma unroll
    for (int j = 0; j < DI; ++j) wx[j] = Wx[i * DI + j];
    bi = bias[i];
  } else {
#pragma unroll
    for (int j = 0; j < DI; ++j) wx[j] = 0.f;
  }

  int row0 = blockIdx.x * rows_per_block;
  int row1 = row0 + rows_per_block;
  if (row1 > BT) row1 = BT;

  for (int r = row0; r < row1; ++r) {
    const float* rp = in + (size_t)r * DI;  // wave-uniform
    float acc = bi;
#pragma unroll
    for (int j = 0; j < DI; ++j) acc = fmaf(rp[j], wx[j], acc);
    if (active) xp[(size_t)r * HH + i] = acc;
  }
}

// ---------------------------------------------------------------------------
// Kernel 2: sequential scan, one batch element per block, lane = state.
//   ah = ah + 0.1*(-ah + W_h h + xp_t);  h = retanh(ah) + noise_t
// W_h row in VGPRs (100 regs/thread); h broadcast via LDS (uniform b128 reads
// = conflict-free broadcast). Output projection (DO=2) fused via shuffle
// reduction. xp is read in-place from the hstore region (2-step prefetch,
// read of [b,t,:] always precedes its overwrite).
// ---------------------------------------------------------------------------
__global__ __launch_bounds__(128) void k_scan(
    const float* __restrict__ noise, const float* __restrict__ Wh,
    const float* __restrict__ Wy, const float* __restrict__ ah0,
    float* out, float* hstore /* aliases xp staging */) {
  const int b = blockIdx.x;
  const int i = threadIdx.x;
  const bool active = (i < HH);

  __shared__ __align__(16) float h_lds[128];
  __shared__ float red[2];

  float wh[HH];
  float wy0 = 0.f, wy1 = 0.f;
  float ah = 0.f;
  if (active) {
#pragma unroll
    for (int j = 0; j < HH; ++j) wh[j] = Wh[i * HH + j];
    wy0 = Wy[i];
    wy1 = Wy[HH + i];
    ah = ah0[i];
  } else {
#pragma unroll
    for (int j = 0; j < HH; ++j) wh[j] = 0.f;
  }

  // initial h = retanh(ah0)  (no noise on the initial state)
  {
    float e = __expf(-2.f * ah);
    float h0 = (ah > 0.f) ? (1.f - e) / (1.f + e) : 0.f;
    h_lds[i] = active ? h0 : 0.f;
  }
  __syncthreads();

  const float* xp_base = hstore;  // in-place staging
  const size_t base = ((size_t)b * TT) * HH + i;

  // 2-deep prefetch of xp/noise
  float xpA = 0.f, nzA = 0.f, xpB = 0.f, nzB = 0.f;
  if (active) {
    xpA = xp_base[base];
    nzA = noise[base];
    xpB = xp_base[base + HH];
    nzB = noise[base + HH];
  }

#define RNN_STEP(XPcur, NZcur, tcur)                                        \
  {                                                                         \
    const int tpf = (tcur) + 2;                                             \
    float nxp = 0.f, nnz = 0.f;                                             \
    if (active && tpf < TT) {                                               \
      nxp = xp_base[base + (size_t)tpf * HH];                               \
      nnz = noise[base + (size_t)tpf * HH];                                 \
    }                                                                       \
    float dot = 0.f;                                                        \
    const float4* h4 = (const float4*)h_lds;                                \
    _Pragma("unroll") for (int j = 0; j < HH / 4; ++j) {                    \
      float4 hv = h4[j];                                                    \
      dot = fmaf(wh[4 * j + 0], hv.x, dot);                                 \
      dot = fmaf(wh[4 * j + 1], hv.y, dot);                                 \
      dot = fmaf(wh[4 * j + 2], hv.z, dot);                                 \
      dot = fmaf(wh[4 * j + 3], hv.w, dot);                                 \
    }                                                                       \
    ah = ah + 0.1f * (dot + XPcur - ah);                                    \
    float e = __expf(-2.f * ah);                                            \
    float h = (ah > 0.f) ? (1.f - e) / (1.f + e) : 0.f;                     \
    h += NZcur;                                                             \
    if (!active) h = 0.f;                                                   \
    float p0 = h * wy0, p1 = h * wy1;                                       \
    _Pragma("unroll") for (int k = 32; k >= 1; k >>= 1) {                   \
      p0 += __shfl_xor(p0, k, 64);                                          \
      p1 += __shfl_xor(p1, k, 64);                                          \
    }                                                                       \
    __syncthreads(); /* all h_lds reads of this step done */                \
    if (active) {                                                           \
      h_lds[i] = h;                                                         \
      hstore[base + (size_t)(tcur)*HH] = h;                                 \
    }                                                                       \
    if (i == 64) {                                                          \
      red[0] = p0;                                                          \
      red[1] = p1;                                                          \
    }                                                                       \
    __syncthreads(); /* new h + partials visible */                         \
    if (i == 0) {                                                           \
      size_t ob = ((size_t)b * TT + (tcur)) * DOUT;                         \
      out[ob + 0] = p0 + red[0];                                            \
      out[ob + 1] = p1 + red[1];                                            \
    }                                                                       \
    XPcur = nxp;                                                            \
    NZcur = nnz;                                                            \
  }

  for (int t = 0; t < TT; t += 2) {
    RNN_STEP(xpA, nzA, t);
    RNN_STEP(xpB, nzB, t + 1);
  }
#undef RNN_STEP
}

// ---------------------------------------------------------------------------
// Launch
// ---------------------------------------------------------------------------
extern "C" void kernel_launch(void* const* d_in, const int* in_sizes, int n_in,
                              void* d_out, int out_size, void* d_ws,
                              size_t ws_size, hipStream_t stream) {
  const float* input = (const float*)d_in[0];   // [B,T,DI]
  const float* noise = (const float*)d_in[1];   // [B,T,H]
  const float* W_x = (const float*)d_in[2];     // [H,DI]
  const float* b_ah = (const float*)d_in[3];    // [H]
  const float* W_h = (const float*)d_in[4];     // [H,H]
  const float* W_y = (const float*)d_in[5];     // [DO,H]
  const float* ah0 = (const float*)d_in[6];     // [H]

  float* out = (float*)d_out;                   // [B,T,DO] first
  float* hstore = out + (size_t)BB * TT * DOUT; // [B,T,H] second

  // K1: input projection, xp staged into hstore region (overwritten by K2).
  const int nblk1 = 2048;
  const int rows_per_block = (BT + nblk1 - 1) / nblk1;  // 128
  k_inproj<<<nblk1, 128, 0, stream>>>(input, W_x, b_ah, hstore,
                                      rows_per_block);

  // K2: sequential scan, one block per batch element.
  k_scan<<<BB, 128, 0, stream>>>(noise, W_h, W_y, ah0, out, hstore);
}

// Round 2
// 856.093 us; speedup vs baseline: 1.0320x; 1.0320x over previous
//
#include <hip/hip_runtime.h>
#include <hip/hip_bf16.h>

#define BB 512
#define TT 512
#define HH 100
#define DI 101
#define DOUT 2
#define BT (BB * TT)

// ---------------------------------------------------------------------------
// Kernel 1: xp[bt, i] = dot(input[bt, :], W_x[i, :]) + b[i]
// lane = output state i (100 active of 128). W_x row held in VGPRs (101 regs)
// -> __launch_bounds__(128,3) caps at ~170 VGPR so the array does NOT spill
// (round-1 failure: default bounds spilled wx/wh to scratch, L2-bound).
// input row address is wave-uniform -> scalar/broadcast loads through cache.
// Stores coalesced (lane-contiguous). xp written into the hstore region of
// d_out (overwritten in-place later by the scan kernel).
// ---------------------------------------------------------------------------
__global__ __launch_bounds__(128, 3) void k_inproj(
    const float* __restrict__ in, const float* __restrict__ Wx,
    const float* __restrict__ bias, float* __restrict__ xp,
    int rows_per_block) {
  const int i = threadIdx.x;
  const bool active = (i < HH);

  float wx[DI];
  float bi = 0.f;
  if (active) {
#pragma unroll
    for (int j = 0; j < DI; ++j) wx[j] = Wx[i * DI + j];
    bi = bias[i];
  } else {
#pragma unroll
    for (int j = 0; j < DI; ++j) wx[j] = 0.f;
  }

  int row0 = blockIdx.x * rows_per_block;
  int row1 = row0 + rows_per_block;
  if (row1 > BT) row1 = BT;

  for (int r = row0; r < row1; ++r) {
    const float* rp = in + (size_t)r * DI;  // wave-uniform
    float acc = bi;
#pragma unroll
    for (int j = 0; j < DI; ++j) acc = fmaf(rp[j], wx[j], acc);
    if (active) xp[(size_t)r * HH + i] = acc;
  }
}

// ---------------------------------------------------------------------------
// Kernel 2: sequential scan, one batch element per block, lane = state.
//   ah = ah + 0.1*(-ah + W_h h + xp_t);  h = retanh(ah) + noise_t
// W_h row in VGPRs (100 regs/thread). Grid = 512 blocks = 2 blocks/CU =
// 1 wave/SIMD, so VGPR pressure up to 512 is free -> __launch_bounds__(128,1)
// to forbid spilling (round-1: VGPR_Count=76 => wh[] spilled, 476us).
// h broadcast via LDS float4 reads (wave-uniform address = conflict-free
// broadcast). Double-buffered h_lds -> ONE __syncthreads per step.
// Output projection (DO=2) fused via shuffle reduction.
// xp read in-place from the hstore region (2-step prefetch; the read of
// [b,t+2,:] in step t always precedes its overwrite in step t+2, same lane).
// ---------------------------------------------------------------------------
__global__ __launch_bounds__(128, 1) void k_scan(
    const float* __restrict__ noise, const float* __restrict__ Wh,
    const float* __restrict__ Wy, const float* __restrict__ ah0,
    float* out, float* hstore /* aliases xp staging */) {
  const int b = blockIdx.x;
  const int i = threadIdx.x;
  const bool active = (i < HH);

  __shared__ __align__(16) float h_lds[2][128];
  __shared__ float red[2][2];

  float wh[HH];
  float wy0 = 0.f, wy1 = 0.f;
  float ah = 0.f;
  if (active) {
#pragma unroll
    for (int j = 0; j < HH; ++j) wh[j] = Wh[i * HH + j];
    wy0 = Wy[i];
    wy1 = Wy[HH + i];
    ah = ah0[i];
  } else {
#pragma unroll
    for (int j = 0; j < HH; ++j) wh[j] = 0.f;
  }

  // initial h = retanh(ah0)  (no noise on the initial state)
  {
    float e = __expf(-2.f * ah);
    float h0 = (ah > 0.f) ? (1.f - e) * __builtin_amdgcn_rcpf(1.f + e) : 0.f;
    h_lds[0][i] = active ? h0 : 0.f;
  }
  __syncthreads();

  const float* xp_base = hstore;  // in-place staging
  const size_t base = ((size_t)b * TT) * HH + i;

  // 2-deep prefetch of xp/noise
  float xpA = 0.f, nzA = 0.f, xpB = 0.f, nzB = 0.f;
  if (active) {
    xpA = xp_base[base];
    nzA = noise[base];
    xpB = xp_base[base + HH];
    nzB = noise[base + HH];
  }

#define RNN_STEP(XPcur, NZcur, tcur)                                        \
  {                                                                         \
    const int tpf = (tcur) + 2;                                             \
    float nxp = 0.f, nnz = 0.f;                                             \
    if (active && tpf < TT) {                                               \
      nxp = xp_base[base + (size_t)tpf * HH];                               \
      nnz = noise[base + (size_t)tpf * HH];                                 \
    }                                                                       \
    const float4* h4 = (const float4*)h_lds[(tcur)&1];                      \
    float dot = 0.f;                                                        \
    _Pragma("unroll") for (int j = 0; j < HH / 4; ++j) {                    \
      float4 hv = h4[j];                                                    \
      dot = fmaf(wh[4 * j + 0], hv.x, dot);                                 \
      dot = fmaf(wh[4 * j + 1], hv.y, dot);                                 \
      dot = fmaf(wh[4 * j + 2], hv.z, dot);                                 \
      dot = fmaf(wh[4 * j + 3], hv.w, dot);                                 \
    }                                                                       \
    ah = fmaf(0.1f, dot + XPcur - ah, ah);                                  \
    float e = __expf(-2.f * ah);                                            \
    float h = (ah > 0.f) ? (1.f - e) * __builtin_amdgcn_rcpf(1.f + e) : 0.f;\
    h += NZcur;                                                             \
    if (!active) h = 0.f;                                                   \
    float p0 = h * wy0, p1 = h * wy1;                                       \
    _Pragma("unroll") for (int k = 32; k >= 1; k >>= 1) {                   \
      p0 += __shfl_xor(p0, k, 64);                                          \
      p1 += __shfl_xor(p1, k, 64);                                          \
    }                                                                       \
    h_lds[((tcur) + 1) & 1][i] = h; /* other buffer: no WAR with readers */ \
    if (active) hstore[base + (size_t)(tcur)*HH] = h;                       \
    if (i == 64) {                                                          \
      red[(tcur)&1][0] = p0;                                                \
      red[(tcur)&1][1] = p1;                                                \
    }                                                                       \
    __syncthreads(); /* publishes new h + wave1 partials */                 \
    if (i == 0) {                                                           \
      size_t ob = ((size_t)b * TT + (tcur)) * DOUT;                         \
      out[ob + 0] = p0 + red[(tcur)&1][0];                                  \
      out[ob + 1] = p1 + red[(tcur)&1][1];                                  \
    }                                                                       \
    XPcur = nxp;                                                            \
    NZcur = nnz;                                                            \
  }

  for (int t = 0; t < TT; t += 2) {
    RNN_STEP(xpA, nzA, t);
    RNN_STEP(xpB, nzB, t + 1);
  }
#undef RNN_STEP
}

// ---------------------------------------------------------------------------
// Launch
// ---------------------------------------------------------------------------
extern "C" void kernel_launch(void* const* d_in, const int* in_sizes, int n_in,
                              void* d_out, int out_size, void* d_ws,
                              size_t ws_size, hipStream_t stream) {
  const float* input = (const float*)d_in[0];   // [B,T,DI]
  const float* noise = (const float*)d_in[1];   // [B,T,H]
  const float* W_x = (const float*)d_in[2];     // [H,DI]
  const float* b_ah = (const float*)d_in[3];    // [H]
  const float* W_h = (const float*)d_in[4];     // [H,H]
  const float* W_y = (const float*)d_in[5];     // [DO,H]
  const float* ah0 = (const float*)d_in[6];     // [H]

  float* out = (float*)d_out;                   // [B,T,DO] first
  float* hstore = out + (size_t)BB * TT * DOUT; // [B,T,H] second

  // K1: input projection, xp staged into hstore region (overwritten by K2).
  const int nblk1 = 2048;
  const int rows_per_block = (BT + nblk1 - 1) / nblk1;  // 128
  k_inproj<<<nblk1, 128, 0, stream>>>(input, W_x, b_ah, hstore,
                                      rows_per_block);

  // K2: sequential scan, one block per batch element.
  k_scan<<<BB, 128, 0, stream>>>(noise, W_h, W_y, ah0, out, hstore);
}

// Round 3
// 729.083 us; speedup vs baseline: 1.2118x; 1.1742x over previous
//
#include <hip/hip_runtime.h>
#include <hip/hip_bf16.h>

#define BB 512
#define TT 512
#define HH 100
#define DI 101
#define DOUT 2
#define BT (BB * TT)

// ---------------------------------------------------------------------------
// Kernel 1: xp[r, c] = dot(in[r, :101], Wx[c, :101]) + b[c]
// Block 128 = 64 lane-pairs. Pair p -> cols {p, p+64}; khalf = tid&1 splits K
// (even: k 0..51, odd: k 52..100). W frags: float4 wx[2][13] ~104 regs (small
// arrays survive regalloc; the round-1/2 float[101] did not). 64-row A tile
// staged in LDS with stride 104 dwords so both k-halves are 16B-aligned.
// Each b128 A read (2-addr broadcast, conflict-free) feeds 8 FMAs.
// ---------------------------------------------------------------------------
__global__ __launch_bounds__(128, 2) void k_inproj(
    const float* __restrict__ in, const float* __restrict__ Wx,
    const float* __restrict__ bias, float* __restrict__ xp) {
  const int t = threadIdx.x;
  const int p = t >> 1;    // pair id 0..63
  const int kh = t & 1;    // k half
  const int c0 = p;        // always < 100
  const int c1 = p + 64;
  const bool c1ok = (c1 < HH);

  __shared__ __align__(16) float Atile[64 * 104];

  // --- W fragments (guarded scalar fills; odd half has 49 valid k) ---
  float4 wx0[13], wx1[13];
  {
    const float* w0 = Wx + (size_t)c0 * DI + kh * 52;
    const float* w1 = Wx + (size_t)(c1ok ? c1 : 0) * DI + kh * 52;
    const int nk = kh ? 49 : 52;
#pragma unroll
    for (int j = 0; j < 13; ++j) {
      float a0 = (4 * j + 0 < nk) ? w0[4 * j + 0] : 0.f;
      float a1 = (4 * j + 1 < nk) ? w0[4 * j + 1] : 0.f;
      float a2 = (4 * j + 2 < nk) ? w0[4 * j + 2] : 0.f;
      float a3 = (4 * j + 3 < nk) ? w0[4 * j + 3] : 0.f;
      wx0[j] = make_float4(a0, a1, a2, a3);
      float b0v = (4 * j + 0 < nk) ? w1[4 * j + 0] : 0.f;
      float b1v = (4 * j + 1 < nk) ? w1[4 * j + 1] : 0.f;
      float b2v = (4 * j + 2 < nk) ? w1[4 * j + 2] : 0.f;
      float b3v = (4 * j + 3 < nk) ? w1[4 * j + 3] : 0.f;
      wx1[j] = make_float4(b0v, b1v, b2v, b3v);
    }
  }
  const float bs0 = bias[c0];
  const float bs1 = c1ok ? bias[c1] : 0.f;

  const int row0 = blockIdx.x * 64;

  // --- stage 64 rows into LDS (thread stages its pair's row-half) ---
  {
    const float* rp = in + (size_t)(row0 + p) * DI + kh * 52;
    float* dst = Atile + p * 104 + kh * 52;
#pragma unroll
    for (int j = 0; j < 52; ++j) {
      float v;
      if (kh == 0) v = rp[j];                       // k = j (<101)
      else        v = (52 + j < DI) ? rp[j] : 0.f;  // k = 52+j; pad 101..103=0
      dst[j] = v;
    }
  }
  __syncthreads();

  // --- compute: every thread walks all 64 rows, 2 cols each ---
#pragma unroll 2
  for (int r = 0; r < 64; ++r) {
    const float4* a4 = (const float4*)(Atile + r * 104 + kh * 52);
    float4 s0 = make_float4(0.f, 0.f, 0.f, 0.f);
    float4 s1 = make_float4(0.f, 0.f, 0.f, 0.f);
#pragma unroll
    for (int j = 0; j < 13; ++j) {
      float4 av = a4[j];
      s0.x = fmaf(av.x, wx0[j].x, s0.x);
      s0.y = fmaf(av.y, wx0[j].y, s0.y);
      s0.z = fmaf(av.z, wx0[j].z, s0.z);
      s0.w = fmaf(av.w, wx0[j].w, s0.w);
      s1.x = fmaf(av.x, wx1[j].x, s1.x);
      s1.y = fmaf(av.y, wx1[j].y, s1.y);
      s1.z = fmaf(av.z, wx1[j].z, s1.z);
      s1.w = fmaf(av.w, wx1[j].w, s1.w);
    }
    float p0 = (s0.x + s0.y) + (s0.z + s0.w);
    float p1 = (s1.x + s1.y) + (s1.z + s1.w);
    p0 += __shfl_xor(p0, 1, 64);
    p1 += __shfl_xor(p1, 1, 64);
    if (kh == 0) {
      float* xr = xp + (size_t)(row0 + r) * HH;
      xr[c0] = p0 + bs0;
      if (c1ok) xr[c1] = p1 + bs1;
    }
  }
}

// ---------------------------------------------------------------------------
// Kernel 2: sequential scan. Block 256 = 4 waves; lane pair shares state
// i = 32*wave + (lane>>1); khalf splits the 100-dot (52/48). Weights:
// float4 wh4[13] (52 regs). h double-buffered in LDS (104 floats, pad
// 100..103 zeroed); b128 broadcast reads. One barrier per step. Output
// projection deferred to k_outproj. xp staged in-place in hstore region.
// ---------------------------------------------------------------------------
__global__ __launch_bounds__(256, 2) void k_scan(
    const float* __restrict__ noise, const float* __restrict__ Wh,
    const float* __restrict__ ah0, float* hstore /* aliases xp staging */) {
  const int b = blockIdx.x;
  const int t = threadIdx.x;
  const int w = t >> 6;
  const int l = t & 63;
  const int i = (w << 5) + (l >> 1);  // state 0..127 (active < 100)
  const int kh = l & 1;
  const bool act = (i < HH);
  const int ie = act ? i : 0;  // clamped for safe addresses
  const int hb = kh * 13;      // float4 base into h buffer

  __shared__ __align__(16) float h_lds[2][104];

  // --- weight fragments (odd half: 12 valid float4 + 1 zero) ---
  float4 wh4[13];
  {
    const float4* wr = (const float4*)(Wh + (size_t)ie * HH + kh * 52);
#pragma unroll
    for (int j = 0; j < 13; ++j) {
      if (j < 12 || kh == 0) wh4[j] = wr[j];
      else wh4[j] = make_float4(0.f, 0.f, 0.f, 0.f);
    }
  }

  float ah = ah0[ie];
  // initial h = retanh(ah0) (no noise on initial state)
  {
    float e = __expf(-2.f * ah);
    float h0 = (ah > 0.f) ? (1.f - e) * __builtin_amdgcn_rcpf(1.f + e) : 0.f;
    if (act && kh == 0) h_lds[0][i] = h0;
  }
  if (t < 8) h_lds[t >> 2][100 + (t & 3)] = 0.f;  // zero pads, both buffers
  __syncthreads();

  const float* xp_base = hstore;  // in-place staging
  const size_t bbase = (size_t)b * TT * HH;

  // 2-deep prefetch
  float xpA = xp_base[bbase + ie];
  float nzA = noise[bbase + ie];
  float xpB = xp_base[bbase + HH + ie];
  float nzB = noise[bbase + HH + ie];

#define STEP(XP, NZ, tc)                                                     \
  {                                                                          \
    const int tpf = (tc) + 2;                                                \
    float nxp = 0.f, nnz = 0.f;                                              \
    if (tpf < TT) {                                                          \
      nxp = xp_base[bbase + (size_t)tpf * HH + ie];                          \
      nnz = noise[bbase + (size_t)tpf * HH + ie];                            \
    }                                                                        \
    const float4* h4 = (const float4*)h_lds[(tc)&1];                         \
    float4 acc = make_float4(0.f, 0.f, 0.f, 0.f);                            \
    _Pragma("unroll") for (int j = 0; j < 13; ++j) {                         \
      float4 hv = h4[hb + j];                                                \
      acc.x = fmaf(wh4[j].x, hv.x, acc.x);                                   \
      acc.y = fmaf(wh4[j].y, hv.y, acc.y);                                   \
      acc.z = fmaf(wh4[j].z, hv.z, acc.z);                                   \
      acc.w = fmaf(wh4[j].w, hv.w, acc.w);                                   \
    }                                                                        \
    float d = (acc.x + acc.y) + (acc.z + acc.w);                             \
    d += __shfl_xor(d, 1, 64);                                               \
    ah = fmaf(0.1f, (d + XP) - ah, ah);                                      \
    float e = __expf(-2.f * ah);                                             \
    float h = (ah > 0.f) ? (1.f - e) * __builtin_amdgcn_rcpf(1.f + e) : 0.f; \
    h += NZ;                                                                 \
    if (act && kh == 0) {                                                    \
      h_lds[((tc) + 1) & 1][i] = h;                                          \
      hstore[bbase + (size_t)(tc)*HH + i] = h;                               \
    }                                                                        \
    __syncthreads();                                                         \
    XP = nxp;                                                                \
    NZ = nnz;                                                                \
  }

#pragma unroll 1
  for (int tc = 0; tc < TT; tc += 2) {
    STEP(xpA, nzA, tc);
    STEP(xpB, nzB, tc + 1);
  }
#undef STEP
}

// ---------------------------------------------------------------------------
// Kernel 3: out[r, 0:2] = hstore[r, :] @ Wy^T.  Memory-bound stream of
// hstore (105 MB). Thread-per-row, float4 row loads (row base 400 B, 16B
// aligned), Wy broadcast from LDS, float2 coalesced store.
// ---------------------------------------------------------------------------
__global__ __launch_bounds__(256, 2) void k_outproj(
    const float* __restrict__ hstore, const float* __restrict__ Wy,
    float* __restrict__ out) {
  __shared__ __align__(16) float wy_l[2][HH];
  const int t = threadIdx.x;
  if (t < 2 * HH) {
    int r = t / HH;
    int c = t - r * HH;
    wy_l[r][c] = Wy[t];
  }
  __syncthreads();

  const int row = blockIdx.x * 256 + t;
  const float4* h4 = (const float4*)(hstore + (size_t)row * HH);
  const float4* w0 = (const float4*)wy_l[0];
  const float4* w1 = (const float4*)wy_l[1];
  float4 a0 = make_float4(0.f, 0.f, 0.f, 0.f);
  float4 a1 = make_float4(0.f, 0.f, 0.f, 0.f);
#pragma unroll
  for (int j = 0; j < 25; ++j) {
    float4 hv = h4[j];
    float4 x0 = w0[j];
    float4 x1 = w1[j];
    a0.x = fmaf(hv.x, x0.x, a0.x);
    a0.y = fmaf(hv.y, x0.y, a0.y);
    a0.z = fmaf(hv.z, x0.z, a0.z);
    a0.w = fmaf(hv.w, x0.w, a0.w);
    a1.x = fmaf(hv.x, x1.x, a1.x);
    a1.y = fmaf(hv.y, x1.y, a1.y);
    a1.z = fmaf(hv.z, x1.z, a1.z);
    a1.w = fmaf(hv.w, x1.w, a1.w);
  }
  float d0 = (a0.x + a0.y) + (a0.z + a0.w);
  float d1 = (a1.x + a1.y) + (a1.z + a1.w);
  ((float2*)out)[row] = make_float2(d0, d1);
}

// ---------------------------------------------------------------------------
// Launch
// ---------------------------------------------------------------------------
extern "C" void kernel_launch(void* const* d_in, const int* in_sizes, int n_in,
                              void* d_out, int out_size, void* d_ws,
                              size_t ws_size, hipStream_t stream) {
  const float* input = (const float*)d_in[0];  // [B,T,DI]
  const float* noise = (const float*)d_in[1];  // [B,T,H]
  const float* W_x = (const float*)d_in[2];    // [H,DI]
  const float* b_ah = (const float*)d_in[3];   // [H]
  const float* W_h = (const float*)d_in[4];    // [H,H]
  const float* W_y = (const float*)d_in[5];    // [DO,H]
  const float* ah0 = (const float*)d_in[6];    // [H]

  float* out = (float*)d_out;                    // [B,T,DO]
  float* hstore = out + (size_t)BB * TT * DOUT;  // [B,T,H]

  // K1: input projection -> xp staged into hstore region.
  k_inproj<<<BT / 64, 128, 0, stream>>>(input, W_x, b_ah, hstore);

  // K2: sequential scan (overwrites hstore in place).
  k_scan<<<BB, 256, 0, stream>>>(noise, W_h, ah0, hstore);

  // K3: output projection from final hstore.
  k_outproj<<<BT / 256, 256, 0, stream>>>(hstore, W_y, out);
}